// Round 3
// baseline (6514.876 us; speedup 1.0000x reference)
//
#include <hip/hip_runtime.h>
#include <hip/hip_bf16.h>

// Problem constants (B,D,H,W,C) = (2,32,56,56,96); WS=(2,7,7), SS=(1,3,3)
#define NTOK   200704      // B*D*H*W
#define NWIN   2048        // B * 1024 windows
#define NT     98          // tokens per window (2*7*7)
#define CCH    96
#define HID    384

typedef __attribute__((ext_vector_type(8))) short bf16x8;   // 8 bf16, 4 VGPRs
typedef __attribute__((ext_vector_type(4))) float f32x4;

__device__ __forceinline__ float bf2f(__hip_bfloat16 v) { return __bfloat162float(v); }

// ---------------- Kernel 0: convert weights to bf16 -----------------------
__global__ __launch_bounds__(256) void k0_cvt(
    const float* __restrict__ w1, const float* __restrict__ w2,
    const float* __restrict__ qkvw, const float* __restrict__ pw,
    __hip_bfloat16* __restrict__ w1b, __hip_bfloat16* __restrict__ w2b,
    __hip_bfloat16* __restrict__ qkvwb, __hip_bfloat16* __restrict__ pwb) {
  int i = blockIdx.x * 256 + threadIdx.x;
  if (i < HID * CCH) {
    w1b[i] = __float2bfloat16(w1[i]);
    w2b[i] = __float2bfloat16(w2[i]);
  }
  if (i < 3 * CCH * CCH) qkvwb[i] = __float2bfloat16(qkvw[i]);
  if (i < CCH * CCH)     pwb[i]   = __float2bfloat16(pw[i]);
}

// ---------------- Kernel 1: LN1 + shift + window partition -> xw (bf16) ----
__global__ __launch_bounds__(256) void k1_ln_window(
    const float* __restrict__ x, const float* __restrict__ g,
    const float* __restrict__ bt, __hip_bfloat16* __restrict__ xw) {
  int token = blockIdx.x * 8 + (threadIdx.x >> 5);
  int lane = threadIdx.x & 31;
  if (token >= NTOK) return;
  int wb = token / NT;
  int n  = token - wb * NT;
  int b = wb >> 10;
  int rem = wb & 1023;
  int wd = rem >> 6, wh = (rem >> 3) & 7, ww = rem & 7;
  int id = n / 49, ih = (n / 7) % 7, iw = n % 7;
  int dd = wd * 2 + id + 1; if (dd >= 32) dd -= 32;
  int hh = wh * 7 + ih + 3; if (hh >= 56) hh -= 56;
  int w2 = ww * 7 + iw + 3; if (w2 >= 56) w2 -= 56;
  const float* src = x + ((((size_t)b * 32 + dd) * 56 + hh) * 56 + w2) * CCH;
  float v0 = src[lane], v1 = src[lane + 32], v2 = src[lane + 64];
  float s = v0 + v1 + v2, ss = v0 * v0 + v1 * v1 + v2 * v2;
  #pragma unroll
  for (int off = 16; off; off >>= 1) {
    s  += __shfl_xor(s,  off, 32);
    ss += __shfl_xor(ss, off, 32);
  }
  float m   = s * (1.f / 96.f);
  float inv = rsqrtf(ss * (1.f / 96.f) - m * m + 1e-5f);
  __hip_bfloat16* dst = xw + (size_t)token * CCH;
  dst[lane]      = __float2bfloat16((v0 - m) * inv * g[lane]      + bt[lane]);
  dst[lane + 32] = __float2bfloat16((v1 - m) * inv * g[lane + 32] + bt[lane + 32]);
  dst[lane + 64] = __float2bfloat16((v2 - m) * inv * g[lane + 64] + bt[lane + 64]);
}

// ---------------- Kernel 2: per-window MFMA attention ---------------------
// 4 waves, heads sequential. A-frag: elem j of lane l = M[l&15][(l>>4)*8+j];
// B-frag: B[(l>>4)*8+j][l&15]; C/D: col=l&15, row=(l>>4)*4+reg.
#define XS_S 104    // X row stride (bf16)
#define QK_S 40     // Q/K row stride
#define VT_S 136    // V^T row stride (also P stride)
__global__ __launch_bounds__(256, 2) void k2_attn(
    const __hip_bfloat16* __restrict__ xw, const __hip_bfloat16* __restrict__ qkvwb,
    const float* __restrict__ qkv_b, const float* __restrict__ mask,
    __hip_bfloat16* __restrict__ obuf) {
  __shared__ __align__(16) __hip_bfloat16 U1[112 * VT_S];  // Xs[112][104] then P[112][136]
  __shared__ __align__(16) __hip_bfloat16 Qs[112 * QK_S];
  __shared__ __align__(16) __hip_bfloat16 Ks[112 * QK_S];
  __shared__ __align__(16) __hip_bfloat16 Vts[32 * VT_S];
  int wb = blockIdx.x, tid = threadIdx.x;
  int wid = tid >> 6, lane = tid & 63, lr = lane & 15, lq = lane >> 4;
  int mw = wb & 1023;
  int wd = mw >> 6, wh = (mw >> 3) & 7, ww = mw & 7;
  bool hasmask = (wd == 15) || (wh == 7) || (ww == 7);
  const __hip_bfloat16* xp = xw + (size_t)wb * (NT * CCH);
  const float* mbase = mask + (size_t)mw * (NT * NT);

  for (int h = 0; h < 3; ++h) {
    __syncthreads();   // previous head's P/V reads complete before restaging
    // stage Xs (zero pad rows 98..111); zero Vts tail cols 112..135
    for (int q = tid; q < 112 * 12; q += 256) {
      int n = q / 12, g = q - n * 12;
      bf16x8 v = {0, 0, 0, 0, 0, 0, 0, 0};
      if (n < NT) v = *(const bf16x8*)(xp + n * CCH + g * 8);
      *(bf16x8*)&U1[n * XS_S + g * 8] = v;
    }
    for (int q = tid; q < 32 * 24; q += 256) {
      int d = q / 24, c = 112 + (q - d * 24);
      Vts[d * VT_S + c] = __float2bfloat16(0.f);
    }
    __syncthreads();

    // qkv for head h: 7 mt x 6 ct tiles, K=96
    for (int job = wid; job < 42; job += 4) {
      int mt = job / 6, ct = job - (job / 6) * 6;
      int which = ct >> 1;                       // 0=Q,1=K,2=V
      int grow = which * CCH + h * 32 + (ct & 1) * 16 + lr;
      float bv = qkv_b[grow];
      f32x4 acc = {bv, bv, bv, bv};
      const __hip_bfloat16* wrow = qkvwb + (size_t)grow * CCH;
      #pragma unroll
      for (int ks = 0; ks < 3; ++ks) {
        bf16x8 a = *(const bf16x8*)&U1[(mt * 16 + lr) * XS_S + ks * 32 + lq * 8];
        bf16x8 b = *(const bf16x8*)(wrow + ks * 32 + lq * 8);
        acc = __builtin_amdgcn_mfma_f32_16x16x32_bf16(a, b, acc, 0, 0, 0);
      }
      int d = (ct & 1) * 16 + lr;
      #pragma unroll
      for (int r = 0; r < 4; ++r) {
        int token = mt * 16 + lq * 4 + r;
        if (which == 0)
          Qs[token * QK_S + d] = __float2bfloat16(acc[r] * 0.17677669529663689f);
        else if (which == 1)
          Ks[token * QK_S + d] = __float2bfloat16(acc[r]);
        else
          Vts[d * VT_S + token] = __float2bfloat16(acc[r]);
      }
    }
    __syncthreads();   // Xs dead from here; U1 becomes P

    __hip_bfloat16* Pp = U1;   // [112][136]
    for (int mt = wid; mt < 7; mt += 4) {
      // zero P cols 112..127 of my rows (PV reads k up to 127)
      *(short4*)&Pp[(mt * 16 + lr) * VT_S + 112 + lq * 4] = (short4){0, 0, 0, 0};

      // QK^T: one MFMA per N-tile (K = head dim = 32)
      f32x4 s[7];
      #pragma unroll
      for (int nt = 0; nt < 7; ++nt) s[nt] = {0.f, 0.f, 0.f, 0.f};
      bf16x8 aq = *(const bf16x8*)&Qs[(mt * 16 + lr) * QK_S + lq * 8];
      #pragma unroll
      for (int nt = 0; nt < 7; ++nt) {
        bf16x8 bk = *(const bf16x8*)&Ks[(nt * 16 + lr) * QK_S + lq * 8];
        s[nt] = __builtin_amdgcn_mfma_f32_16x16x32_bf16(aq, bk, s[nt], 0, 0, 0);
      }
      // mask + column bounds
      #pragma unroll
      for (int nt = 0; nt < 7; ++nt) {
        int j = nt * 16 + lr;
        if (j >= NT) {
          s[nt] = {-1e30f, -1e30f, -1e30f, -1e30f};
        } else if (hasmask) {
          #pragma unroll
          for (int r = 0; r < 4; ++r) {
            int i = mt * 16 + lq * 4 + r;
            if (i < NT) s[nt][r] += mbase[i * NT + j];
          }
        }
      }
      // softmax per row (row = (lq, r); spread over 16 lanes x 7 regs)
      #pragma unroll
      for (int r = 0; r < 4; ++r) {
        float m = s[0][r];
        #pragma unroll
        for (int nt = 1; nt < 7; ++nt) m = fmaxf(m, s[nt][r]);
        #pragma unroll
        for (int off = 1; off < 16; off <<= 1) m = fmaxf(m, __shfl_xor(m, off));
        float sum = 0.f;
        #pragma unroll
        for (int nt = 0; nt < 7; ++nt) {
          float e = __expf(s[nt][r] - m);
          s[nt][r] = e;
          sum += e;
        }
        #pragma unroll
        for (int off = 1; off < 16; off <<= 1) sum += __shfl_xor(sum, off);
        float inv = 1.f / sum;
        #pragma unroll
        for (int nt = 0; nt < 7; ++nt)
          Pp[(mt * 16 + lq * 4 + r) * VT_S + nt * 16 + lr] =
              __float2bfloat16(s[nt][r] * inv);
      }
      // PV: O[16 x 32] = P[16 x 128] * V[128 x 32] (tail zeroed)
      bf16x8 ap[4];
      #pragma unroll
      for (int ks = 0; ks < 4; ++ks)
        ap[ks] = *(const bf16x8*)&Pp[(mt * 16 + lr) * VT_S + ks * 32 + lq * 8];
      #pragma unroll
      for (int nt2 = 0; nt2 < 2; ++nt2) {
        f32x4 ao = {0.f, 0.f, 0.f, 0.f};
        #pragma unroll
        for (int ks = 0; ks < 4; ++ks) {
          bf16x8 bv = *(const bf16x8*)&Vts[(nt2 * 16 + lr) * VT_S + ks * 32 + lq * 8];
          ao = __builtin_amdgcn_mfma_f32_16x16x32_bf16(ap[ks], bv, ao, 0, 0, 0);
        }
        #pragma unroll
        for (int r = 0; r < 4; ++r) {
          int token = mt * 16 + lq * 4 + r;
          if (token < NT)
            obuf[((size_t)wb * NT + token) * CCH + h * 32 + nt2 * 16 + lr] =
                __float2bfloat16(ao[r]);
        }
      }
    }
  }
}

// ---------------- Kernel 3: MFMA proj + window-reverse + residual ---------
__global__ __launch_bounds__(256) void k3_proj(
    const __hip_bfloat16* __restrict__ obuf, const float* __restrict__ x,
    const __hip_bfloat16* __restrict__ pwb, const float* __restrict__ pb,
    float* __restrict__ out) {
  __shared__ __align__(16) __hip_bfloat16 os[112 * XS_S];
  int wb = blockIdx.x, tid = threadIdx.x;
  int wid = tid >> 6, lane = tid & 63, lr = lane & 15, lq = lane >> 4;
  const __hip_bfloat16* src = obuf + (size_t)wb * (NT * CCH);
  for (int q = tid; q < 112 * 12; q += 256) {
    int n = q / 12, g = q - n * 12;
    bf16x8 v = {0, 0, 0, 0, 0, 0, 0, 0};
    if (n < NT) v = *(const bf16x8*)(src + n * CCH + g * 8);
    *(bf16x8*)&os[n * XS_S + g * 8] = v;
  }
  __syncthreads();
  int b = wb >> 10, rem = wb & 1023;
  int wd = rem >> 6, wh = (rem >> 3) & 7, ww = rem & 7;
  for (int job = wid; job < 42; job += 4) {
    int mt = job / 6, ct = job - (job / 6) * 6;
    float bv = pb[ct * 16 + lr];
    f32x4 acc = {bv, bv, bv, bv};
    const __hip_bfloat16* wrow = pwb + (size_t)(ct * 16 + lr) * CCH;
    #pragma unroll
    for (int ks = 0; ks < 3; ++ks) {
      bf16x8 a = *(const bf16x8*)&os[(mt * 16 + lr) * XS_S + ks * 32 + lq * 8];
      bf16x8 bw = *(const bf16x8*)(wrow + ks * 32 + lq * 8);
      acc = __builtin_amdgcn_mfma_f32_16x16x32_bf16(a, bw, acc, 0, 0, 0);
    }
    #pragma unroll
    for (int r = 0; r < 4; ++r) {
      int token = mt * 16 + lq * 4 + r;
      if (token < NT) {
        int id = token / 49, r2 = token - id * 49;
        int ih = r2 / 7, iw = r2 - ih * 7;
        int dd = wd * 2 + id + 1; if (dd >= 32) dd -= 32;
        int hh = wh * 7 + ih + 3; if (hh >= 56) hh -= 56;
        int w2 = ww * 7 + iw + 3; if (w2 >= 56) w2 -= 56;
        size_t gi = ((((size_t)b * 32 + dd) * 56 + hh) * 56 + w2) * CCH + ct * 16 + lr;
        out[gi] = x[gi] + acc[r];
      }
    }
  }
}

// ---------------- Kernel 4: MFMA MLP: LN2 + fc1 + GELU + fc2 + residual ---
#define XB_S 104
#define H_S  392
__global__ __launch_bounds__(256, 2) void k4_mlp(
    float* __restrict__ io, const float* __restrict__ g, const float* __restrict__ bt,
    const __hip_bfloat16* __restrict__ w1b, const float* __restrict__ b1,
    const __hip_bfloat16* __restrict__ w2b, const float* __restrict__ b2) {
  __shared__ __hip_bfloat16 Xb[64 * XB_S];
  __shared__ __hip_bfloat16 Hs[64 * H_S];
  int tid = threadIdx.x;
  size_t base = (size_t)blockIdx.x * 64 * CCH;
  {
    int grp = tid >> 5, lane = tid & 31;
    for (int t = grp; t < 64; t += 8) {
      const float* src = io + base + (size_t)t * CCH;
      float v0 = src[lane], v1 = src[lane + 32], v2 = src[lane + 64];
      float s = v0 + v1 + v2, ss = v0 * v0 + v1 * v1 + v2 * v2;
      #pragma unroll
      for (int off = 16; off; off >>= 1) {
        s  += __shfl_xor(s,  off, 32);
        ss += __shfl_xor(ss, off, 32);
      }
      float m   = s * (1.f / 96.f);
      float inv = rsqrtf(ss * (1.f / 96.f) - m * m + 1e-5f);
      Xb[t * XB_S + lane]      = __float2bfloat16((v0 - m) * inv * g[lane]      + bt[lane]);
      Xb[t * XB_S + lane + 32] = __float2bfloat16((v1 - m) * inv * g[lane + 32] + bt[lane + 32]);
      Xb[t * XB_S + lane + 64] = __float2bfloat16((v2 - m) * inv * g[lane + 64] + bt[lane + 64]);
    }
  }
  __syncthreads();
  int wid = tid >> 6, lane = tid & 63, lr = lane & 15, lq = lane >> 4;
  {
    f32x4 acc[4][6];
    #pragma unroll
    for (int nt = 0; nt < 6; ++nt) {
      float bv = b1[96 * wid + 16 * nt + lr];
      #pragma unroll
      for (int m = 0; m < 4; ++m) acc[m][nt] = {bv, bv, bv, bv};
    }
    #pragma unroll
    for (int ks = 0; ks < 3; ++ks) {
      int k0 = ks * 32;
      bf16x8 a[4];
      #pragma unroll
      for (int m = 0; m < 4; ++m)
        a[m] = *(const bf16x8*)&Xb[(16 * m + lr) * XB_S + k0 + lq * 8];
      #pragma unroll
      for (int nt = 0; nt < 6; ++nt) {
        bf16x8 b = *(const bf16x8*)&w1b[(size_t)(96 * wid + 16 * nt + lr) * CCH + k0 + lq * 8];
        #pragma unroll
        for (int m = 0; m < 4; ++m)
          acc[m][nt] = __builtin_amdgcn_mfma_f32_16x16x32_bf16(a[m], b, acc[m][nt], 0, 0, 0);
      }
    }
    #pragma unroll
    for (int m = 0; m < 4; ++m)
      #pragma unroll
      for (int nt = 0; nt < 6; ++nt)
        #pragma unroll
        for (int r = 0; r < 4; ++r) {
          float v = acc[m][nt][r];
          v = 0.5f * v * (1.f + erff(v * 0.70710678118654752f));
          Hs[(16 * m + lq * 4 + r) * H_S + 96 * wid + 16 * nt + lr] = __float2bfloat16(v);
        }
  }
  __syncthreads();
  {
    f32x4 acc2[6];
    #pragma unroll
    for (int nt = 0; nt < 6; ++nt) {
      float bv = b2[16 * nt + lr];
      acc2[nt] = {bv, bv, bv, bv};
    }
    for (int k0 = 0; k0 < HID; k0 += 32) {
      bf16x8 a = *(const bf16x8*)&Hs[(16 * wid + lr) * H_S + k0 + lq * 8];
      #pragma unroll
      for (int nt = 0; nt < 6; ++nt) {
        bf16x8 b = *(const bf16x8*)&w2b[(size_t)(16 * nt + lr) * HID + k0 + lq * 8];
        acc2[nt] = __builtin_amdgcn_mfma_f32_16x16x32_bf16(a, b, acc2[nt], 0, 0, 0);
      }
    }
    #pragma unroll
    for (int nt = 0; nt < 6; ++nt)
      #pragma unroll
      for (int r = 0; r < 4; ++r) {
        int t = 16 * wid + lq * 4 + r;
        int c = 16 * nt + lr;
        size_t gi = base + (size_t)t * CCH + c;
        io[gi] = io[gi] + acc2[nt][r];
      }
  }
}

extern "C" void kernel_launch(void* const* d_in, const int* in_sizes, int n_in,
                              void* d_out, int out_size, void* d_ws, size_t ws_size,
                              hipStream_t stream) {
  const float* x    = (const float*)d_in[0];
  const float* mask = (const float*)d_in[1];
  const float* n1g  = (const float*)d_in[2];
  const float* n1b  = (const float*)d_in[3];
  const float* qkvw = (const float*)d_in[4];
  const float* qkvb = (const float*)d_in[5];
  const float* pw   = (const float*)d_in[6];
  const float* pb   = (const float*)d_in[7];
  const float* n2g  = (const float*)d_in[8];
  const float* n2b  = (const float*)d_in[9];
  const float* w1   = (const float*)d_in[10];
  const float* b1   = (const float*)d_in[11];
  const float* w2   = (const float*)d_in[12];
  const float* b2   = (const float*)d_in[13];
  float* out = (float*)d_out;

  __hip_bfloat16* xw    = (__hip_bfloat16*)d_ws;
  __hip_bfloat16* obuf  = xw + (size_t)NTOK * CCH;
  __hip_bfloat16* w1b   = obuf + (size_t)NTOK * CCH;
  __hip_bfloat16* w2b   = w1b + HID * CCH;
  __hip_bfloat16* qkvwb = w2b + HID * CCH;
  __hip_bfloat16* pwb   = qkvwb + 3 * CCH * CCH;

  k0_cvt<<<(HID * CCH + 255) / 256, 256, 0, stream>>>(w1, w2, qkvw, pw, w1b, w2b, qkvwb, pwb);
  k1_ln_window<<<NTOK / 8, 256, 0, stream>>>(x, n1g, n1b, xw);
  k2_attn<<<NWIN, 256, 0, stream>>>(xw, qkvwb, qkvb, mask, obuf);
  k3_proj<<<NWIN, 256, 0, stream>>>(obuf, x, pwb, pb, out);
  k4_mlp<<<NTOK / 64, 256, 0, stream>>>(out, n2g, n2b, w1b, b1, w2b, b2);
}

// Round 4
// 729.853 us; speedup vs baseline: 8.9263x; 8.9263x over previous
//
#include <hip/hip_runtime.h>
#include <hip/hip_bf16.h>

// Problem constants (B,D,H,W,C) = (2,32,56,56,96); WS=(2,7,7), SS=(1,3,3)
#define NTOK   200704      // B*D*H*W
#define NWIN   2048        // B * 1024 windows
#define NT     98          // tokens per window (2*7*7)
#define CCH    96
#define HID    384

typedef __attribute__((ext_vector_type(8))) short bf16x8;   // 8 bf16, 4 VGPRs
typedef __attribute__((ext_vector_type(4))) float f32x4;

__device__ __forceinline__ float bf2f(__hip_bfloat16 v) { return __bfloat162float(v); }

// ---------------- Kernel 0: convert weights to bf16 -----------------------
__global__ __launch_bounds__(256) void k0_cvt(
    const float* __restrict__ w1, const float* __restrict__ w2,
    const float* __restrict__ qkvw, const float* __restrict__ pw,
    __hip_bfloat16* __restrict__ w1b, __hip_bfloat16* __restrict__ w2b,
    __hip_bfloat16* __restrict__ qkvwb, __hip_bfloat16* __restrict__ pwb) {
  int i = blockIdx.x * 256 + threadIdx.x;
  if (i < HID * CCH) {
    w1b[i] = __float2bfloat16(w1[i]);
    w2b[i] = __float2bfloat16(w2[i]);
  }
  if (i < 3 * CCH * CCH) qkvwb[i] = __float2bfloat16(qkvw[i]);
  if (i < CCH * CCH)     pwb[i]   = __float2bfloat16(pw[i]);
}

// ---------------- Kernel 1: LN1 + shift + window partition -> xw (bf16) ----
__global__ __launch_bounds__(256) void k1_ln_window(
    const float* __restrict__ x, const float* __restrict__ g,
    const float* __restrict__ bt, __hip_bfloat16* __restrict__ xw) {
  int token = blockIdx.x * 8 + (threadIdx.x >> 5);
  int lane = threadIdx.x & 31;
  if (token >= NTOK) return;
  int wb = token / NT;
  int n  = token - wb * NT;
  int b = wb >> 10;
  int rem = wb & 1023;
  int wd = rem >> 6, wh = (rem >> 3) & 7, ww = rem & 7;
  int id = n / 49, ih = (n / 7) % 7, iw = n % 7;
  int dd = wd * 2 + id + 1; if (dd >= 32) dd -= 32;
  int hh = wh * 7 + ih + 3; if (hh >= 56) hh -= 56;
  int w2 = ww * 7 + iw + 3; if (w2 >= 56) w2 -= 56;
  const float* src = x + ((((size_t)b * 32 + dd) * 56 + hh) * 56 + w2) * CCH;
  float v0 = src[lane], v1 = src[lane + 32], v2 = src[lane + 64];
  float s = v0 + v1 + v2, ss = v0 * v0 + v1 * v1 + v2 * v2;
  #pragma unroll
  for (int off = 16; off; off >>= 1) {
    s  += __shfl_xor(s,  off, 32);
    ss += __shfl_xor(ss, off, 32);
  }
  float m   = s * (1.f / 96.f);
  float inv = rsqrtf(ss * (1.f / 96.f) - m * m + 1e-5f);
  __hip_bfloat16* dst = xw + (size_t)token * CCH;
  dst[lane]      = __float2bfloat16((v0 - m) * inv * g[lane]      + bt[lane]);
  dst[lane + 32] = __float2bfloat16((v1 - m) * inv * g[lane + 32] + bt[lane + 32]);
  dst[lane + 64] = __float2bfloat16((v2 - m) * inv * g[lane + 64] + bt[lane + 64]);
}

// ---------------- Kernel 2: per-(window,head) MFMA attention --------------
// 4 waves, NO head loop (grid y = head). A-frag: elem j of lane l =
// M[l&15][(l>>4)*8+j]; B-frag: B[(l>>4)*8+j][l&15]; C/D: col=l&15,row=(l>>4)*4+reg.
#define XS_S 104    // X row stride (bf16)
#define QK_S 40     // Q/K row stride
#define VT_S 136    // V^T row stride (also P stride)
__global__ __launch_bounds__(256) void k2_attn(
    const __hip_bfloat16* __restrict__ xw, const __hip_bfloat16* __restrict__ qkvwb,
    const float* __restrict__ qkv_b, const float* __restrict__ mask,
    __hip_bfloat16* __restrict__ obuf) {
  __shared__ __align__(16) __hip_bfloat16 U1[112 * VT_S];  // Xs[112][104] then P[112][136]
  __shared__ __align__(16) __hip_bfloat16 Qs[112 * QK_S];
  __shared__ __align__(16) __hip_bfloat16 Ks[112 * QK_S];
  __shared__ __align__(16) __hip_bfloat16 Vts[32 * VT_S];
  int wb = blockIdx.x, h = blockIdx.y, tid = threadIdx.x;
  int wid = tid >> 6, lane = tid & 63, lr = lane & 15, lq = lane >> 4;
  int mw = wb & 1023;
  int wd = mw >> 6, wh = (mw >> 3) & 7, ww = mw & 7;
  bool hasmask = (wd == 15) || (wh == 7) || (ww == 7);
  const __hip_bfloat16* xp = xw + (size_t)wb * (NT * CCH);
  const float* mbase = mask + (size_t)mw * (NT * NT);

  // stage Xs (zero pad rows 98..111); zero Vts tail cols 112..135
  for (int q = tid; q < 112 * 12; q += 256) {
    int n = q / 12, g = q - n * 12;
    bf16x8 v = {0, 0, 0, 0, 0, 0, 0, 0};
    if (n < NT) v = *(const bf16x8*)(xp + n * CCH + g * 8);
    *(bf16x8*)&U1[n * XS_S + g * 8] = v;
  }
  for (int q = tid; q < 32 * 24; q += 256) {
    int d = q / 24, c = 112 + (q - d * 24);
    Vts[d * VT_S + c] = __float2bfloat16(0.f);
  }
  __syncthreads();

  // qkv for head h: 7 mt x 6 ct tiles, K=96
  for (int job = wid; job < 42; job += 4) {
    int mt = job / 6, ct = job - (job / 6) * 6;
    int which = ct >> 1;                       // 0=Q,1=K,2=V
    int grow = which * CCH + h * 32 + (ct & 1) * 16 + lr;
    float bv = qkv_b[grow];
    f32x4 acc = {bv, bv, bv, bv};
    const __hip_bfloat16* wrow = qkvwb + (size_t)grow * CCH;
    #pragma unroll
    for (int ks = 0; ks < 3; ++ks) {
      bf16x8 a = *(const bf16x8*)&U1[(mt * 16 + lr) * XS_S + ks * 32 + lq * 8];
      bf16x8 b = *(const bf16x8*)(wrow + ks * 32 + lq * 8);
      acc = __builtin_amdgcn_mfma_f32_16x16x32_bf16(a, b, acc, 0, 0, 0);
    }
    int d = (ct & 1) * 16 + lr;
    #pragma unroll
    for (int r = 0; r < 4; ++r) {
      int token = mt * 16 + lq * 4 + r;
      if (which == 0)
        Qs[token * QK_S + d] = __float2bfloat16(acc[r] * 0.17677669529663689f);
      else if (which == 1)
        Ks[token * QK_S + d] = __float2bfloat16(acc[r]);
      else
        Vts[d * VT_S + token] = __float2bfloat16(acc[r]);
    }
  }
  __syncthreads();   // Xs dead from here; U1 becomes P

  __hip_bfloat16* Pp = U1;   // [112][136]
  for (int mt = wid; mt < 7; mt += 4) {
    // zero P cols 112..127 of my rows (PV reads k up to 127)
    *(short4*)&Pp[(mt * 16 + lr) * VT_S + 112 + lq * 4] = (short4){0, 0, 0, 0};

    // QK^T: one MFMA per N-tile (K = head dim = 32)
    f32x4 s[7];
    #pragma unroll
    for (int nt = 0; nt < 7; ++nt) s[nt] = {0.f, 0.f, 0.f, 0.f};
    bf16x8 aq = *(const bf16x8*)&Qs[(mt * 16 + lr) * QK_S + lq * 8];
    #pragma unroll
    for (int nt = 0; nt < 7; ++nt) {
      bf16x8 bk = *(const bf16x8*)&Ks[(nt * 16 + lr) * QK_S + lq * 8];
      s[nt] = __builtin_amdgcn_mfma_f32_16x16x32_bf16(aq, bk, s[nt], 0, 0, 0);
    }
    // mask + column bounds
    #pragma unroll
    for (int nt = 0; nt < 7; ++nt) {
      int j = nt * 16 + lr;
      if (j >= NT) {
        s[nt] = {-1e30f, -1e30f, -1e30f, -1e30f};
      } else if (hasmask) {
        #pragma unroll
        for (int r = 0; r < 4; ++r) {
          int i = mt * 16 + lq * 4 + r;
          if (i < NT) s[nt][r] += mbase[i * NT + j];
        }
      }
    }
    // softmax per row (row = (lq, r); spread over 16 lanes x 7 regs)
    #pragma unroll
    for (int r = 0; r < 4; ++r) {
      float m = s[0][r];
      #pragma unroll
      for (int nt = 1; nt < 7; ++nt) m = fmaxf(m, s[nt][r]);
      #pragma unroll
      for (int off = 1; off < 16; off <<= 1) m = fmaxf(m, __shfl_xor(m, off));
      float sum = 0.f;
      #pragma unroll
      for (int nt = 0; nt < 7; ++nt) {
        float e = __expf(s[nt][r] - m);
        s[nt][r] = e;
        sum += e;
      }
      #pragma unroll
      for (int off = 1; off < 16; off <<= 1) sum += __shfl_xor(sum, off);
      float inv = 1.f / sum;
      #pragma unroll
      for (int nt = 0; nt < 7; ++nt)
        Pp[(mt * 16 + lq * 4 + r) * VT_S + nt * 16 + lr] =
            __float2bfloat16(s[nt][r] * inv);
    }
    // PV: O[16 x 32] = P[16 x 128] * V[128 x 32] (tail zeroed)
    bf16x8 ap[4];
    #pragma unroll
    for (int ks = 0; ks < 4; ++ks)
      ap[ks] = *(const bf16x8*)&Pp[(mt * 16 + lr) * VT_S + ks * 32 + lq * 8];
    #pragma unroll
    for (int nt2 = 0; nt2 < 2; ++nt2) {
      f32x4 ao = {0.f, 0.f, 0.f, 0.f};
      #pragma unroll
      for (int ks = 0; ks < 4; ++ks) {
        bf16x8 bv = *(const bf16x8*)&Vts[(nt2 * 16 + lr) * VT_S + ks * 32 + lq * 8];
        ao = __builtin_amdgcn_mfma_f32_16x16x32_bf16(ap[ks], bv, ao, 0, 0, 0);
      }
      #pragma unroll
      for (int r = 0; r < 4; ++r) {
        int token = mt * 16 + lq * 4 + r;
        if (token < NT)
          obuf[((size_t)wb * NT + token) * CCH + h * 32 + nt2 * 16 + lr] =
              __float2bfloat16(ao[r]);
      }
    }
  }
}

// ---------------- Kernel 3: MFMA proj + window-reverse + residual ---------
__global__ __launch_bounds__(256) void k3_proj(
    const __hip_bfloat16* __restrict__ obuf, const float* __restrict__ x,
    const __hip_bfloat16* __restrict__ pwb, const float* __restrict__ pb,
    float* __restrict__ out) {
  __shared__ __align__(16) __hip_bfloat16 os[112 * XS_S];
  int wb = blockIdx.x, tid = threadIdx.x;
  int wid = tid >> 6, lane = tid & 63, lr = lane & 15, lq = lane >> 4;
  const __hip_bfloat16* src = obuf + (size_t)wb * (NT * CCH);
  for (int q = tid; q < 112 * 12; q += 256) {
    int n = q / 12, g = q - n * 12;
    bf16x8 v = {0, 0, 0, 0, 0, 0, 0, 0};
    if (n < NT) v = *(const bf16x8*)(src + n * CCH + g * 8);
    *(bf16x8*)&os[n * XS_S + g * 8] = v;
  }
  __syncthreads();
  int b = wb >> 10, rem = wb & 1023;
  int wd = rem >> 6, wh = (rem >> 3) & 7, ww = rem & 7;
  for (int job = wid; job < 42; job += 4) {
    int mt = job / 6, ct = job - (job / 6) * 6;
    float bv = pb[ct * 16 + lr];
    f32x4 acc = {bv, bv, bv, bv};
    const __hip_bfloat16* wrow = pwb + (size_t)(ct * 16 + lr) * CCH;
    #pragma unroll
    for (int ks = 0; ks < 3; ++ks) {
      bf16x8 a = *(const bf16x8*)&os[(mt * 16 + lr) * XS_S + ks * 32 + lq * 8];
      bf16x8 bw = *(const bf16x8*)(wrow + ks * 32 + lq * 8);
      acc = __builtin_amdgcn_mfma_f32_16x16x32_bf16(a, bw, acc, 0, 0, 0);
    }
    #pragma unroll
    for (int r = 0; r < 4; ++r) {
      int token = mt * 16 + lq * 4 + r;
      if (token < NT) {
        int id = token / 49, r2 = token - id * 49;
        int ih = r2 / 7, iw = r2 - ih * 7;
        int dd = wd * 2 + id + 1; if (dd >= 32) dd -= 32;
        int hh = wh * 7 + ih + 3; if (hh >= 56) hh -= 56;
        int w2 = ww * 7 + iw + 3; if (w2 >= 56) w2 -= 56;
        size_t gi = ((((size_t)b * 32 + dd) * 56 + hh) * 56 + w2) * CCH + ct * 16 + lr;
        out[gi] = x[gi] + acc[r];
      }
    }
  }
}

// ---------------- Kernel 4: MFMA MLP: LN2 + fc1 + GELU + fc2 + residual ---
#define XB_S 104
#define H_S  392
__global__ __launch_bounds__(256, 2) void k4_mlp(
    float* __restrict__ io, const float* __restrict__ g, const float* __restrict__ bt,
    const __hip_bfloat16* __restrict__ w1b, const float* __restrict__ b1,
    const __hip_bfloat16* __restrict__ w2b, const float* __restrict__ b2) {
  __shared__ __hip_bfloat16 Xb[64 * XB_S];
  __shared__ __hip_bfloat16 Hs[64 * H_S];
  int tid = threadIdx.x;
  size_t base = (size_t)blockIdx.x * 64 * CCH;
  {
    int grp = tid >> 5, lane = tid & 31;
    for (int t = grp; t < 64; t += 8) {
      const float* src = io + base + (size_t)t * CCH;
      float v0 = src[lane], v1 = src[lane + 32], v2 = src[lane + 64];
      float s = v0 + v1 + v2, ss = v0 * v0 + v1 * v1 + v2 * v2;
      #pragma unroll
      for (int off = 16; off; off >>= 1) {
        s  += __shfl_xor(s,  off, 32);
        ss += __shfl_xor(ss, off, 32);
      }
      float m   = s * (1.f / 96.f);
      float inv = rsqrtf(ss * (1.f / 96.f) - m * m + 1e-5f);
      Xb[t * XB_S + lane]      = __float2bfloat16((v0 - m) * inv * g[lane]      + bt[lane]);
      Xb[t * XB_S + lane + 32] = __float2bfloat16((v1 - m) * inv * g[lane + 32] + bt[lane + 32]);
      Xb[t * XB_S + lane + 64] = __float2bfloat16((v2 - m) * inv * g[lane + 64] + bt[lane + 64]);
    }
  }
  __syncthreads();
  int wid = tid >> 6, lane = tid & 63, lr = lane & 15, lq = lane >> 4;
  {
    f32x4 acc[4][6];
    #pragma unroll
    for (int nt = 0; nt < 6; ++nt) {
      float bv = b1[96 * wid + 16 * nt + lr];
      #pragma unroll
      for (int m = 0; m < 4; ++m) acc[m][nt] = {bv, bv, bv, bv};
    }
    #pragma unroll
    for (int ks = 0; ks < 3; ++ks) {
      int k0 = ks * 32;
      bf16x8 a[4];
      #pragma unroll
      for (int m = 0; m < 4; ++m)
        a[m] = *(const bf16x8*)&Xb[(16 * m + lr) * XB_S + k0 + lq * 8];
      #pragma unroll
      for (int nt = 0; nt < 6; ++nt) {
        bf16x8 b = *(const bf16x8*)&w1b[(size_t)(96 * wid + 16 * nt + lr) * CCH + k0 + lq * 8];
        #pragma unroll
        for (int m = 0; m < 4; ++m)
          acc[m][nt] = __builtin_amdgcn_mfma_f32_16x16x32_bf16(a[m], b, acc[m][nt], 0, 0, 0);
      }
    }
    #pragma unroll
    for (int m = 0; m < 4; ++m)
      #pragma unroll
      for (int nt = 0; nt < 6; ++nt)
        #pragma unroll
        for (int r = 0; r < 4; ++r) {
          float v = acc[m][nt][r];
          v = 0.5f * v * (1.f + erff(v * 0.70710678118654752f));
          Hs[(16 * m + lq * 4 + r) * H_S + 96 * wid + 16 * nt + lr] = __float2bfloat16(v);
        }
  }
  __syncthreads();
  {
    f32x4 acc2[6];
    #pragma unroll
    for (int nt = 0; nt < 6; ++nt) {
      float bv = b2[16 * nt + lr];
      acc2[nt] = {bv, bv, bv, bv};
    }
    for (int k0 = 0; k0 < HID; k0 += 32) {
      bf16x8 a = *(const bf16x8*)&Hs[(16 * wid + lr) * H_S + k0 + lq * 8];
      #pragma unroll
      for (int nt = 0; nt < 6; ++nt) {
        bf16x8 b = *(const bf16x8*)&w2b[(size_t)(16 * nt + lr) * HID + k0 + lq * 8];
        acc2[nt] = __builtin_amdgcn_mfma_f32_16x16x32_bf16(a, b, acc2[nt], 0, 0, 0);
      }
    }
    #pragma unroll
    for (int nt = 0; nt < 6; ++nt)
      #pragma unroll
      for (int r = 0; r < 4; ++r) {
        int t = 16 * wid + lq * 4 + r;
        int c = 16 * nt + lr;
        size_t gi = base + (size_t)t * CCH + c;
        io[gi] = io[gi] + acc2[nt][r];
      }
  }
}

extern "C" void kernel_launch(void* const* d_in, const int* in_sizes, int n_in,
                              void* d_out, int out_size, void* d_ws, size_t ws_size,
                              hipStream_t stream) {
  const float* x    = (const float*)d_in[0];
  const float* mask = (const float*)d_in[1];
  const float* n1g  = (const float*)d_in[2];
  const float* n1b  = (const float*)d_in[3];
  const float* qkvw = (const float*)d_in[4];
  const float* qkvb = (const float*)d_in[5];
  const float* pw   = (const float*)d_in[6];
  const float* pb   = (const float*)d_in[7];
  const float* n2g  = (const float*)d_in[8];
  const float* n2b  = (const float*)d_in[9];
  const float* w1   = (const float*)d_in[10];
  const float* b1   = (const float*)d_in[11];
  const float* w2   = (const float*)d_in[12];
  const float* b2   = (const float*)d_in[13];
  float* out = (float*)d_out;

  __hip_bfloat16* xw    = (__hip_bfloat16*)d_ws;
  __hip_bfloat16* obuf  = xw + (size_t)NTOK * CCH;
  __hip_bfloat16* w1b   = obuf + (size_t)NTOK * CCH;
  __hip_bfloat16* w2b   = w1b + HID * CCH;
  __hip_bfloat16* qkvwb = w2b + HID * CCH;
  __hip_bfloat16* pwb   = qkvwb + 3 * CCH * CCH;

  k0_cvt<<<(HID * CCH + 255) / 256, 256, 0, stream>>>(w1, w2, qkvw, pw, w1b, w2b, qkvwb, pwb);
  k1_ln_window<<<NTOK / 8, 256, 0, stream>>>(x, n1g, n1b, xw);
  k2_attn<<<dim3(NWIN, 3), 256, 0, stream>>>(xw, qkvwb, qkvb, mask, obuf);
  k3_proj<<<NWIN, 256, 0, stream>>>(obuf, x, pwb, pb, out);
  k4_mlp<<<NTOK / 64, 256, 0, stream>>>(out, n2g, n2b, w1b, b1, w2b, b2);
}

// Round 5
// 616.466 us; speedup vs baseline: 10.5681x; 1.1839x over previous
//
#include <hip/hip_runtime.h>
#include <hip/hip_bf16.h>

// Problem constants (B,D,H,W,C) = (2,32,56,56,96); WS=(2,7,7), SS=(1,3,3)
#define NTOK   200704      // B*D*H*W
#define NWIN   2048        // B * 1024 windows
#define NT     98          // tokens per window (2*7*7)
#define CCH    96
#define HID    384

typedef __attribute__((ext_vector_type(8))) short bf16x8;   // 8 bf16, 4 VGPRs
typedef __attribute__((ext_vector_type(4))) float f32x4;

__device__ __forceinline__ float bf2f(__hip_bfloat16 v) { return __bfloat162float(v); }

// ---------------- Kernel 0: convert weights to bf16 -----------------------
__global__ __launch_bounds__(256) void k0_cvt(
    const float* __restrict__ w1, const float* __restrict__ w2,
    const float* __restrict__ qkvw, const float* __restrict__ pw,
    __hip_bfloat16* __restrict__ w1b, __hip_bfloat16* __restrict__ w2b,
    __hip_bfloat16* __restrict__ qkvwb, __hip_bfloat16* __restrict__ pwb) {
  int i = blockIdx.x * 256 + threadIdx.x;
  if (i < HID * CCH) {
    w1b[i] = __float2bfloat16(w1[i]);
    w2b[i] = __float2bfloat16(w2[i]);
  }
  if (i < 3 * CCH * CCH) qkvwb[i] = __float2bfloat16(qkvw[i]);
  if (i < CCH * CCH)     pwb[i]   = __float2bfloat16(pw[i]);
}

// ---------------- Kernel 1: LN1 + shift + window partition -> xw (bf16) ----
__global__ __launch_bounds__(256) void k1_ln_window(
    const float* __restrict__ x, const float* __restrict__ g,
    const float* __restrict__ bt, __hip_bfloat16* __restrict__ xw) {
  int token = blockIdx.x * 8 + (threadIdx.x >> 5);
  int lane = threadIdx.x & 31;
  if (token >= NTOK) return;
  int wb = token / NT;
  int n  = token - wb * NT;
  int b = wb >> 10;
  int rem = wb & 1023;
  int wd = rem >> 6, wh = (rem >> 3) & 7, ww = rem & 7;
  int id = n / 49, ih = (n / 7) % 7, iw = n % 7;
  int dd = wd * 2 + id + 1; if (dd >= 32) dd -= 32;
  int hh = wh * 7 + ih + 3; if (hh >= 56) hh -= 56;
  int w2 = ww * 7 + iw + 3; if (w2 >= 56) w2 -= 56;
  const float* src = x + ((((size_t)b * 32 + dd) * 56 + hh) * 56 + w2) * CCH;
  float v0 = src[lane], v1 = src[lane + 32], v2 = src[lane + 64];
  float s = v0 + v1 + v2, ss = v0 * v0 + v1 * v1 + v2 * v2;
  #pragma unroll
  for (int off = 16; off; off >>= 1) {
    s  += __shfl_xor(s,  off, 32);
    ss += __shfl_xor(ss, off, 32);
  }
  float m   = s * (1.f / 96.f);
  float inv = rsqrtf(ss * (1.f / 96.f) - m * m + 1e-5f);
  __hip_bfloat16* dst = xw + (size_t)token * CCH;
  dst[lane]      = __float2bfloat16((v0 - m) * inv * g[lane]      + bt[lane]);
  dst[lane + 32] = __float2bfloat16((v1 - m) * inv * g[lane + 32] + bt[lane + 32]);
  dst[lane + 64] = __float2bfloat16((v2 - m) * inv * g[lane + 64] + bt[lane + 64]);
}

// ---------------- Kernel 2: per-(window,head) MFMA attention --------------
// Flat grid: bid -> (win = bid/3, head = bid%3) so the 3 head-blocks of a
// window are dispatch-adjacent (xw window stays L2-resident).
// LDS 46.8 KB -> 3 blocks/CU. PV = 3 MFMA (K=96) + fp32 rank-2 tail for
// tokens 96/97 (P tail from softmax regs via shfl, V tail via scalar LDS).
// A-frag: elem j of lane l = M[l&15][(l>>4)*8+j]; B-frag: B[(l>>4)*8+j][l&15];
// C/D: col=l&15, row=(l>>4)*4+reg.
#define XS_S 104    // X row stride (bf16); also P stride (cols 0..95 used)
#define QK_S 40     // Q/K row stride
#define VT_S 104    // V^T row stride (cols = tokens 0..97 used)
__global__ __launch_bounds__(256) void k2_attn(
    const __hip_bfloat16* __restrict__ xw, const __hip_bfloat16* __restrict__ qkvwb,
    const float* __restrict__ qkv_b, const float* __restrict__ mask,
    __hip_bfloat16* __restrict__ obuf) {
  __shared__ __align__(16) __hip_bfloat16 U1[112 * XS_S];  // Xs then P
  __shared__ __align__(16) __hip_bfloat16 Qs[112 * QK_S];
  __shared__ __align__(16) __hip_bfloat16 Ks[112 * QK_S];
  __shared__ __align__(16) __hip_bfloat16 Vts[32 * VT_S];
  int bid = blockIdx.x, tid = threadIdx.x;
  int wb = bid / 3, h = bid - wb * 3;
  int wid = tid >> 6, lane = tid & 63, lr = lane & 15, lq = lane >> 4;
  int mw = wb & 1023;
  int wd = mw >> 6, wh = (mw >> 3) & 7, ww = mw & 7;
  bool hasmask = (wd == 15) || (wh == 7) || (ww == 7);
  const __hip_bfloat16* xp = xw + (size_t)wb * (NT * CCH);
  const float* mbase = mask + (size_t)mw * (NT * NT);

  // stage Xs (zero pad rows 98..111)
  for (int q = tid; q < 112 * 12; q += 256) {
    int n = q / 12, g = q - n * 12;
    bf16x8 v = {0, 0, 0, 0, 0, 0, 0, 0};
    if (n < NT) v = *(const bf16x8*)(xp + n * CCH + g * 8);
    *(bf16x8*)&U1[n * XS_S + g * 8] = v;
  }
  __syncthreads();

  // qkv for head h: 7 mt x 6 ct tiles, K=96
  for (int job = wid; job < 42; job += 4) {
    int mt = job / 6, ct = job - (job / 6) * 6;
    int which = ct >> 1;                       // 0=Q,1=K,2=V
    int grow = which * CCH + h * 32 + (ct & 1) * 16 + lr;
    float bv = qkv_b[grow];
    f32x4 acc = {bv, bv, bv, bv};
    const __hip_bfloat16* wrow = qkvwb + (size_t)grow * CCH;
    #pragma unroll
    for (int ks = 0; ks < 3; ++ks) {
      bf16x8 a = *(const bf16x8*)&U1[(mt * 16 + lr) * XS_S + ks * 32 + lq * 8];
      bf16x8 b = *(const bf16x8*)(wrow + ks * 32 + lq * 8);
      acc = __builtin_amdgcn_mfma_f32_16x16x32_bf16(a, b, acc, 0, 0, 0);
    }
    int d = (ct & 1) * 16 + lr;
    #pragma unroll
    for (int r = 0; r < 4; ++r) {
      int token = mt * 16 + lq * 4 + r;
      if (which == 0)
        Qs[token * QK_S + d] = __float2bfloat16(acc[r] * 0.17677669529663689f);
      else if (which == 1)
        Ks[token * QK_S + d] = __float2bfloat16(acc[r]);
      else if (token < NT)
        Vts[d * VT_S + token] = __float2bfloat16(acc[r]);
    }
  }
  __syncthreads();   // Xs dead from here; U1 becomes P (cols 0..95)

  __hip_bfloat16* Pp = U1;   // [112][104], cols 0..95 used by PV MFMA
  for (int mt = wid; mt < 7; mt += 4) {
    // QK^T: one MFMA per N-tile (K = head dim = 32)
    f32x4 s[7];
    #pragma unroll
    for (int nt = 0; nt < 7; ++nt) s[nt] = {0.f, 0.f, 0.f, 0.f};
    bf16x8 aq = *(const bf16x8*)&Qs[(mt * 16 + lr) * QK_S + lq * 8];
    #pragma unroll
    for (int nt = 0; nt < 7; ++nt) {
      bf16x8 bk = *(const bf16x8*)&Ks[(nt * 16 + lr) * QK_S + lq * 8];
      s[nt] = __builtin_amdgcn_mfma_f32_16x16x32_bf16(aq, bk, s[nt], 0, 0, 0);
    }
    // mask + column bounds
    #pragma unroll
    for (int nt = 0; nt < 7; ++nt) {
      int j = nt * 16 + lr;
      if (j >= NT) {
        s[nt] = {-1e30f, -1e30f, -1e30f, -1e30f};
      } else if (hasmask) {
        #pragma unroll
        for (int r = 0; r < 4; ++r) {
          int i = mt * 16 + lq * 4 + r;
          if (i < NT) s[nt][r] += mbase[i * NT + j];
        }
      }
    }
    // softmax per row (row = (lq, r); spread over 16 lanes x 7 regs)
    #pragma unroll
    for (int r = 0; r < 4; ++r) {
      float m = s[0][r];
      #pragma unroll
      for (int nt = 1; nt < 7; ++nt) m = fmaxf(m, s[nt][r]);
      #pragma unroll
      for (int off = 1; off < 16; off <<= 1) m = fmaxf(m, __shfl_xor(m, off));
      float sum = 0.f;
      #pragma unroll
      for (int nt = 0; nt < 7; ++nt) {
        float e = __expf(s[nt][r] - m);
        s[nt][r] = e;
        sum += e;
      }
      #pragma unroll
      for (int off = 1; off < 16; off <<= 1) sum += __shfl_xor(sum, off);
      float inv = 1.f / sum;
      #pragma unroll
      for (int nt = 0; nt < 7; ++nt) s[nt][r] *= inv;
      // write P cols 0..95 (nt 0..5); nt=6 (tokens 96/97) stays in regs
      #pragma unroll
      for (int nt = 0; nt < 6; ++nt)
        Pp[(mt * 16 + lq * 4 + r) * XS_S + nt * 16 + lr] =
            __float2bfloat16(s[nt][r]);
    }
    // PV: O[16 x 32] = P[16 x 96] * V[96 x 32] + rank-2 tail (tokens 96,97)
    bf16x8 ap[3];
    #pragma unroll
    for (int ks = 0; ks < 3; ++ks)
      ap[ks] = *(const bf16x8*)&Pp[(mt * 16 + lr) * XS_S + ks * 32 + lq * 8];
    #pragma unroll
    for (int nt2 = 0; nt2 < 2; ++nt2) {
      f32x4 ao = {0.f, 0.f, 0.f, 0.f};
      #pragma unroll
      for (int ks = 0; ks < 3; ++ks) {
        bf16x8 bv = *(const bf16x8*)&Vts[(nt2 * 16 + lr) * VT_S + ks * 32 + lq * 8];
        ao = __builtin_amdgcn_mfma_f32_16x16x32_bf16(ap[ks], bv, ao, 0, 0, 0);
      }
      float v96 = bf2f(Vts[(nt2 * 16 + lr) * VT_S + 96]);
      float v97 = bf2f(Vts[(nt2 * 16 + lr) * VT_S + 97]);
      #pragma unroll
      for (int r = 0; r < 4; ++r) {
        float p96 = __shfl(s[6][r], lane & 48);        // P[row][96] from lane lq*16+0
        float p97 = __shfl(s[6][r], (lane & 48) | 1);  // P[row][97] from lane lq*16+1
        ao[r] += p96 * v96 + p97 * v97;
        int token = mt * 16 + lq * 4 + r;
        if (token < NT)
          obuf[((size_t)wb * NT + token) * CCH + h * 32 + nt2 * 16 + lr] =
              __float2bfloat16(ao[r]);
      }
    }
  }
}

// ---------------- Kernel 3: MFMA proj + window-reverse + residual ---------
__global__ __launch_bounds__(256) void k3_proj(
    const __hip_bfloat16* __restrict__ obuf, const float* __restrict__ x,
    const __hip_bfloat16* __restrict__ pwb, const float* __restrict__ pb,
    float* __restrict__ out) {
  __shared__ __align__(16) __hip_bfloat16 os[112 * XS_S];
  int wb = blockIdx.x, tid = threadIdx.x;
  int wid = tid >> 6, lane = tid & 63, lr = lane & 15, lq = lane >> 4;
  const __hip_bfloat16* src = obuf + (size_t)wb * (NT * CCH);
  for (int q = tid; q < 112 * 12; q += 256) {
    int n = q / 12, g = q - n * 12;
    bf16x8 v = {0, 0, 0, 0, 0, 0, 0, 0};
    if (n < NT) v = *(const bf16x8*)(src + n * CCH + g * 8);
    *(bf16x8*)&os[n * XS_S + g * 8] = v;
  }
  __syncthreads();
  int b = wb >> 10, rem = wb & 1023;
  int wd = rem >> 6, wh = (rem >> 3) & 7, ww = rem & 7;
  for (int job = wid; job < 42; job += 4) {
    int mt = job / 6, ct = job - (job / 6) * 6;
    float bv = pb[ct * 16 + lr];
    f32x4 acc = {bv, bv, bv, bv};
    const __hip_bfloat16* wrow = pwb + (size_t)(ct * 16 + lr) * CCH;
    #pragma unroll
    for (int ks = 0; ks < 3; ++ks) {
      bf16x8 a = *(const bf16x8*)&os[(mt * 16 + lr) * XS_S + ks * 32 + lq * 8];
      bf16x8 bw = *(const bf16x8*)(wrow + ks * 32 + lq * 8);
      acc = __builtin_amdgcn_mfma_f32_16x16x32_bf16(a, bw, acc, 0, 0, 0);
    }
    #pragma unroll
    for (int r = 0; r < 4; ++r) {
      int token = mt * 16 + lq * 4 + r;
      if (token < NT) {
        int id = token / 49, r2 = token - id * 49;
        int ih = r2 / 7, iw = r2 - ih * 7;
        int dd = wd * 2 + id + 1; if (dd >= 32) dd -= 32;
        int hh = wh * 7 + ih + 3; if (hh >= 56) hh -= 56;
        int w2 = ww * 7 + iw + 3; if (w2 >= 56) w2 -= 56;
        size_t gi = ((((size_t)b * 32 + dd) * 56 + hh) * 56 + w2) * CCH + ct * 16 + lr;
        out[gi] = x[gi] + acc[r];
      }
    }
  }
}

// ---------------- Kernel 4: MFMA MLP: LN2 + fc1 + GELU + fc2 + residual ---
#define XB_S 104
#define H_S  392
__global__ __launch_bounds__(256, 2) void k4_mlp(
    float* __restrict__ io, const float* __restrict__ g, const float* __restrict__ bt,
    const __hip_bfloat16* __restrict__ w1b, const float* __restrict__ b1,
    const __hip_bfloat16* __restrict__ w2b, const float* __restrict__ b2) {
  __shared__ __hip_bfloat16 Xb[64 * XB_S];
  __shared__ __hip_bfloat16 Hs[64 * H_S];
  int tid = threadIdx.x;
  size_t base = (size_t)blockIdx.x * 64 * CCH;
  {
    int grp = tid >> 5, lane = tid & 31;
    for (int t = grp; t < 64; t += 8) {
      const float* src = io + base + (size_t)t * CCH;
      float v0 = src[lane], v1 = src[lane + 32], v2 = src[lane + 64];
      float s = v0 + v1 + v2, ss = v0 * v0 + v1 * v1 + v2 * v2;
      #pragma unroll
      for (int off = 16; off; off >>= 1) {
        s  += __shfl_xor(s,  off, 32);
        ss += __shfl_xor(ss, off, 32);
      }
      float m   = s * (1.f / 96.f);
      float inv = rsqrtf(ss * (1.f / 96.f) - m * m + 1e-5f);
      Xb[t * XB_S + lane]      = __float2bfloat16((v0 - m) * inv * g[lane]      + bt[lane]);
      Xb[t * XB_S + lane + 32] = __float2bfloat16((v1 - m) * inv * g[lane + 32] + bt[lane + 32]);
      Xb[t * XB_S + lane + 64] = __float2bfloat16((v2 - m) * inv * g[lane + 64] + bt[lane + 64]);
    }
  }
  __syncthreads();
  int wid = tid >> 6, lane = tid & 63, lr = lane & 15, lq = lane >> 4;
  {
    f32x4 acc[4][6];
    #pragma unroll
    for (int nt = 0; nt < 6; ++nt) {
      float bv = b1[96 * wid + 16 * nt + lr];
      #pragma unroll
      for (int m = 0; m < 4; ++m) acc[m][nt] = {bv, bv, bv, bv};
    }
    #pragma unroll
    for (int ks = 0; ks < 3; ++ks) {
      int k0 = ks * 32;
      bf16x8 a[4];
      #pragma unroll
      for (int m = 0; m < 4; ++m)
        a[m] = *(const bf16x8*)&Xb[(16 * m + lr) * XB_S + k0 + lq * 8];
      #pragma unroll
      for (int nt = 0; nt < 6; ++nt) {
        bf16x8 b = *(const bf16x8*)&w1b[(size_t)(96 * wid + 16 * nt + lr) * CCH + k0 + lq * 8];
        #pragma unroll
        for (int m = 0; m < 4; ++m)
          acc[m][nt] = __builtin_amdgcn_mfma_f32_16x16x32_bf16(a[m], b, acc[m][nt], 0, 0, 0);
      }
    }
    #pragma unroll
    for (int m = 0; m < 4; ++m)
      #pragma unroll
      for (int nt = 0; nt < 6; ++nt)
        #pragma unroll
        for (int r = 0; r < 4; ++r) {
          float v = acc[m][nt][r];
          v = 0.5f * v * (1.f + erff(v * 0.70710678118654752f));
          Hs[(16 * m + lq * 4 + r) * H_S + 96 * wid + 16 * nt + lr] = __float2bfloat16(v);
        }
  }
  __syncthreads();
  {
    f32x4 acc2[6];
    #pragma unroll
    for (int nt = 0; nt < 6; ++nt) {
      float bv = b2[16 * nt + lr];
      acc2[nt] = {bv, bv, bv, bv};
    }
    for (int k0 = 0; k0 < HID; k0 += 32) {
      bf16x8 a = *(const bf16x8*)&Hs[(16 * wid + lr) * H_S + k0 + lq * 8];
      #pragma unroll
      for (int nt = 0; nt < 6; ++nt) {
        bf16x8 b = *(const bf16x8*)&w2b[(size_t)(16 * nt + lr) * HID + k0 + lq * 8];
        acc2[nt] = __builtin_amdgcn_mfma_f32_16x16x32_bf16(a, b, acc2[nt], 0, 0, 0);
      }
    }
    #pragma unroll
    for (int nt = 0; nt < 6; ++nt)
      #pragma unroll
      for (int r = 0; r < 4; ++r) {
        int t = 16 * wid + lq * 4 + r;
        int c = 16 * nt + lr;
        size_t gi = base + (size_t)t * CCH + c;
        io[gi] = io[gi] + acc2[nt][r];
      }
  }
}

extern "C" void kernel_launch(void* const* d_in, const int* in_sizes, int n_in,
                              void* d_out, int out_size, void* d_ws, size_t ws_size,
                              hipStream_t stream) {
  const float* x    = (const float*)d_in[0];
  const float* mask = (const float*)d_in[1];
  const float* n1g  = (const float*)d_in[2];
  const float* n1b  = (const float*)d_in[3];
  const float* qkvw = (const float*)d_in[4];
  const float* qkvb = (const float*)d_in[5];
  const float* pw   = (const float*)d_in[6];
  const float* pb   = (const float*)d_in[7];
  const float* n2g  = (const float*)d_in[8];
  const float* n2b  = (const float*)d_in[9];
  const float* w1   = (const float*)d_in[10];
  const float* b1   = (const float*)d_in[11];
  const float* w2   = (const float*)d_in[12];
  const float* b2   = (const float*)d_in[13];
  float* out = (float*)d_out;

  __hip_bfloat16* xw    = (__hip_bfloat16*)d_ws;
  __hip_bfloat16* obuf  = xw + (size_t)NTOK * CCH;
  __hip_bfloat16* w1b   = obuf + (size_t)NTOK * CCH;
  __hip_bfloat16* w2b   = w1b + HID * CCH;
  __hip_bfloat16* qkvwb = w2b + HID * CCH;
  __hip_bfloat16* pwb   = qkvwb + 3 * CCH * CCH;

  k0_cvt<<<(HID * CCH + 255) / 256, 256, 0, stream>>>(w1, w2, qkvw, pw, w1b, w2b, qkvwb, pwb);
  k1_ln_window<<<NTOK / 8, 256, 0, stream>>>(x, n1g, n1b, xw);
  k2_attn<<<NWIN * 3, 256, 0, stream>>>(xw, qkvwb, qkvb, mask, obuf);
  k3_proj<<<NWIN, 256, 0, stream>>>(obuf, x, pwb, pb, out);
  k4_mlp<<<NTOK / 64, 256, 0, stream>>>(out, n2g, n2b, w1b, b1, w2b, b2);
}